// Round 9
// baseline (1668.654 us; speedup 1.0000x reference)
//
#include <hip/hip_runtime.h>

// GraphEncoder: GINE-style GNN, D=768, 4 layers. fp32 I/O, f16 intermediates +
// f16 MFMA GEMMs, fp32 accumulate/LN/scatter math.
//
// Round 11: GEMM -> 256x256 4-phase counted-vmcnt schedule (T3+T4, from the
// verified 8-phase template, simplified but keeping the essentials):
//   512 thr / 8 waves (2Mx4N), BK=64, 128KB dbuf LDS. Per K-tile:
//   {issue 2 prefetch, s_waitcnt vmcnt(2) [never 0 mid-loop], s_barrier} then
//   4 phases of {8 ds_read_b128, 2 prefetch, setprio(1), 16 MFMA, setprio(0),
//   s_barrier}. Steady state: 8 loads for current tile land while 2..8 loads
//   for the next tile stay in flight ACROSS the barriers.
//   Race guards: phase-3 barrier protects buffer overwrite (ds_reads retire
//   before their MFMAs via compiler lgkmcnt); bias preloaded BEFORE the K-loop
//   so no stray VMEM corrupts vmcnt counting; sched_barrier(0) pins the
//   tile-top boundary against ds_read hoisting.
// r8 lesson (2-phase@128^2 = regression) matches the guide's regime gate:
// counted vmcnt pays only with the multi-phase 256^2 schedule.
//
// Kept: operand-swapped MFMA epilogue (8B f16x4 C stores), XCD-chunked grid
// swizzle, LDS XOR swizzle (slot ^= row&7, both sides), __expf gelu,
// wave-per-row LN kernels, deduped bond encoder, linked-list gather.
//
// Workspace: [WT 12x768x768 f16 | Q 50048x768 f16 | h Nx768 f16 | T | key | ids3]
// d_out (Nx768 fp32, 153.6MB): low half = f16 U scratch; head/next parked at
// +120MB (clobbered only by the final fp32 LN write). A-tile overreads
// (<=176 rows past M) land in adjacent mapped ws regions; outputs row-guarded.

#define DM 768
#define NLAYERS 4
#define CHUNK 50048  // row capacity for Q (multiple of 128, >= N)

typedef _Float16 f16;
typedef __attribute__((ext_vector_type(8))) _Float16 f16x8;
typedef __attribute__((ext_vector_type(4))) _Float16 f16x4;
typedef __attribute__((ext_vector_type(4))) float f32x4;

// gelu(x) = 0.5x(1+tanh(0.79788456(x+0.044715x^3))), tanh via exp:
// tanh(u) = sign(u) * (1 - a)/(1 + a), a = exp(-2|u|)  (a->0 saturates cleanly)
__device__ __forceinline__ float gelu_f(float x) {
    float u = 0.7978845608028654f * (x + 0.044715f * x * x * x);
    float a = __expf(-2.0f * fabsf(u));
    float t = (1.0f - a) / (1.0f + a);
    t = copysignf(t, u);
    return 0.5f * x * (1.0f + t);
}
__device__ __forceinline__ void async16(const void* g, void* l) {
    __builtin_amdgcn_global_load_lds((const __attribute__((address_space(1))) void*)g,
                                     (__attribute__((address_space(3))) void*)l,
                                     16, 0, 0);
}

// bijective XCD-chunked swizzle (m204): XCD k = b%8 gets a contiguous range of
// work ids; within the range, original b/8 order is preserved.
__device__ __forceinline__ int xcd_swizzle(int b, int nb) {
    int xcd = b & 7;
    int pos = b >> 3;
    int q = nb >> 3, r = nb & 7;
    int base = (xcd < r) ? xcd * (q + 1) : r * (q + 1) + (xcd - r) * q;
    return base + pos;
}

// -------- weight transpose + fp32->fp16: Wt[n][k] = W[k][n], 768x768 ----------
__global__ __launch_bounds__(256) void transpose768(
    const float* __restrict__ W, f16* __restrict__ Wt) {
    __shared__ float t[32][33];
    int tx = threadIdx.x, ty = threadIdx.y;
    int c0 = blockIdx.x * 32, r0 = blockIdx.y * 32;
    #pragma unroll
    for (int j = 0; j < 32; j += 8) t[ty + j][tx] = W[(r0 + ty + j) * DM + c0 + tx];
    __syncthreads();
    #pragma unroll
    for (int j = 0; j < 32; j += 8) Wt[(long)(c0 + ty + j) * DM + r0 + tx] = (f16)t[tx][ty + j];
}

// -------- embedding-sum + LayerNorm, wave-per-row (no LDS, no barriers) ------
__global__ __launch_bounds__(256) void embed_ln_wave(
    const int* __restrict__ ids, int F, int V,
    const float* __restrict__ emb,
    const float* __restrict__ g, const float* __restrict__ b,
    f16* __restrict__ out, int M) {
    int row = blockIdx.x * 4 + (threadIdx.x >> 6);
    if (row >= M) return;
    int lane = threadIdx.x & 63;
    int base = lane * 12;

    float v[12];
    #pragma unroll
    for (int j = 0; j < 12; ++j) v[j] = 0.f;
    for (int f = 0; f < F; ++f) {
        int id = ids[(long)row * F + f];
        const float* r = emb + ((long)f * V + id) * DM + base;
        float4 r0 = *(const float4*)&r[0];
        float4 r1 = *(const float4*)&r[4];
        float4 r2 = *(const float4*)&r[8];
        v[0] += r0.x; v[1] += r0.y; v[2]  += r0.z; v[3]  += r0.w;
        v[4] += r1.x; v[5] += r1.y; v[6]  += r1.z; v[7]  += r1.w;
        v[8] += r2.x; v[9] += r2.y; v[10] += r2.z; v[11] += r2.w;
    }
    float s1 = 0.f, s2 = 0.f;
    #pragma unroll
    for (int j = 0; j < 12; ++j) { s1 += v[j]; s2 += v[j] * v[j]; }
    #pragma unroll
    for (int off = 32; off > 0; off >>= 1) {
        s1 += __shfl_xor(s1, off);
        s2 += __shfl_xor(s2, off);
    }
    float mean = s1 * (1.f / DM);
    float var = s2 * (1.f / DM) - mean * mean;
    float rstd = rsqrtf(var + 1e-5f);

    float4 gv0 = *(const float4*)&g[base], gv1 = *(const float4*)&g[base + 4], gv2 = *(const float4*)&g[base + 8];
    float4 bv0 = *(const float4*)&b[base], bv1 = *(const float4*)&b[base + 4], bv2 = *(const float4*)&b[base + 8];
    float gg[12] = {gv0.x, gv0.y, gv0.z, gv0.w, gv1.x, gv1.y, gv1.z, gv1.w, gv2.x, gv2.y, gv2.z, gv2.w};
    float bb[12] = {bv0.x, bv0.y, bv0.z, bv0.w, bv1.x, bv1.y, bv1.z, bv1.w, bv2.x, bv2.y, bv2.z, bv2.w};
    f16* o = out + (long)row * DM + base;
    #pragma unroll
    for (int q = 0; q < 3; ++q) {
        f16x4 ov;
        #pragma unroll
        for (int r = 0; r < 4; ++r)
            ov[r] = (f16)((v[q * 4 + r] - mean) * rstd * gg[q * 4 + r] + bb[q * 4 + r]);
        *(f16x4*)&o[q * 4] = ov;
    }
}

// -------- gelu(U) + h_in -> LayerNorm -> out, wave-per-row ----------
template <typename OUT>
__global__ __launch_bounds__(256) void gelu_res_ln_wave(
    const f16* __restrict__ U, const f16* __restrict__ hin,
    const float* __restrict__ g, const float* __restrict__ b,
    OUT* __restrict__ out, int M) {
    int row = blockIdx.x * 4 + (threadIdx.x >> 6);
    if (row >= M) return;
    int lane = threadIdx.x & 63;
    int base = lane * 12;

    const f16* up = U + (long)row * DM + base;
    const f16* hp = hin + (long)row * DM + base;
    float v[12];
    #pragma unroll
    for (int q = 0; q < 3; ++q) {
        f16x4 uv = *(const f16x4*)&up[q * 4];
        f16x4 hv = *(const f16x4*)&hp[q * 4];
        #pragma unroll
        for (int r = 0; r < 4; ++r)
            v[q * 4 + r] = gelu_f((float)uv[r]) + (float)hv[r];
    }
    float s1 = 0.f, s2 = 0.f;
    #pragma unroll
    for (int j = 0; j < 12; ++j) { s1 += v[j]; s2 += v[j] * v[j]; }
    #pragma unroll
    for (int off = 32; off > 0; off >>= 1) {
        s1 += __shfl_xor(s1, off);
        s2 += __shfl_xor(s2, off);
    }
    float mean = s1 * (1.f / DM);
    float var = s2 * (1.f / DM) - mean * mean;
    float rstd = rsqrtf(var + 1e-5f);

    float4 gv0 = *(const float4*)&g[base], gv1 = *(const float4*)&g[base + 4], gv2 = *(const float4*)&g[base + 8];
    float4 bv0 = *(const float4*)&b[base], bv1 = *(const float4*)&b[base + 4], bv2 = *(const float4*)&b[base + 8];
    float gg[12] = {gv0.x, gv0.y, gv0.z, gv0.w, gv1.x, gv1.y, gv1.z, gv1.w, gv2.x, gv2.y, gv2.z, gv2.w};
    float bb[12] = {bv0.x, bv0.y, bv0.z, bv0.w, bv1.x, bv1.y, bv1.z, bv1.w, bv2.x, bv2.y, bv2.z, bv2.w};
    #pragma unroll
    for (int q = 0; q < 3; ++q) {
        float w0 = (v[q * 4 + 0] - mean) * rstd * gg[q * 4 + 0] + bb[q * 4 + 0];
        float w1 = (v[q * 4 + 1] - mean) * rstd * gg[q * 4 + 1] + bb[q * 4 + 1];
        float w2 = (v[q * 4 + 2] - mean) * rstd * gg[q * 4 + 2] + bb[q * 4 + 2];
        float w3 = (v[q * 4 + 3] - mean) * rstd * gg[q * 4 + 3] + bb[q * 4 + 3];
        if constexpr (sizeof(OUT) == 2) {
            f16x4 ov; ov[0] = (f16)w0; ov[1] = (f16)w1; ov[2] = (f16)w2; ov[3] = (f16)w3;
            *(f16x4*)&out[(long)row * DM + base + q * 4] = ov;
        } else {
            float4 ov; ov.x = w0; ov.y = w1; ov.z = w2; ov.w = w3;
            *(float4*)&out[(long)row * DM + base + q * 4] = ov;
        }
    }
}

// -------- bond-combo helpers: ids for all V^3 combos; per-edge key ----------
__global__ __launch_bounds__(256) void make_combo_ids(
    int V, int nC, int* __restrict__ ids) {
    int c = blockIdx.x * 256 + threadIdx.x;
    if (c >= nC) return;
    ids[c * 3 + 0] = c / (V * V);
    ids[c * 3 + 1] = (c / V) % V;
    ids[c * 3 + 2] = c % V;
}
__global__ __launch_bounds__(256) void make_key_kernel(
    const int* __restrict__ ea, int E, int V, int* __restrict__ key) {
    int e = blockIdx.x * 256 + threadIdx.x;
    if (e >= E) return;
    key[e] = (ea[e * 3 + 0] * V + ea[e * 3 + 1]) * V + ea[e * 3 + 2];
}

// -------- build per-dst edge linked list (once; edge_index is layer-invariant) --
__global__ __launch_bounds__(256) void build_list_kernel(
    const int* __restrict__ ei, int E,
    int* __restrict__ head, int* __restrict__ nxt) {
    int e = blockIdx.x * 256 + threadIdx.x;
    if (e >= E) return;
    int dst = ei[E + e];
    nxt[e] = atomicExch(&head[dst], e);  // device-scope; order irrelevant (sum)
}

// -------- per-node gather aggregation: z[n] = h[n] + sum relu(h[src]+T[key]) --
__global__ __launch_bounds__(256) void gather_agg_kernel(
    const int* __restrict__ ei,
    const int* __restrict__ head, const int* __restrict__ nxt,
    const int* __restrict__ key,
    const f16* __restrict__ h, const f16* __restrict__ T,
    f16* __restrict__ z, int N) {
    int node = blockIdx.x * 4 + (threadIdx.x >> 6);
    if (node >= N) return;
    int lane = threadIdx.x & 63;
    int base = lane * 12;

    const f16* hr = h + (long)node * DM + base;
    f16x4 v0 = *(const f16x4*)&hr[0];
    f16x4 v1 = *(const f16x4*)&hr[4];
    f16x4 v2 = *(const f16x4*)&hr[8];
    float acc[12];
    #pragma unroll
    for (int j = 0; j < 4; ++j) {
        acc[j]     = (float)v0[j];
        acc[4 + j] = (float)v1[j];
        acc[8 + j] = (float)v2[j];
    }

    int ecur = head[node];
    while (ecur >= 0) {
        int enext = nxt[ecur];          // issue chase early; rows overlap it
        int src = ei[ecur];
        int kq = key[ecur];
        const f16* sr = h + (long)src * DM + base;
        const f16* er = T + (long)kq * DM + base;
        f16x4 a0 = *(const f16x4*)&sr[0];
        f16x4 a1 = *(const f16x4*)&sr[4];
        f16x4 a2 = *(const f16x4*)&sr[8];
        f16x4 b0 = *(const f16x4*)&er[0];
        f16x4 b1 = *(const f16x4*)&er[4];
        f16x4 b2 = *(const f16x4*)&er[8];
        #pragma unroll
        for (int j = 0; j < 4; ++j) {
            float m0 = (float)a0[j] + (float)b0[j];
            float m1 = (float)a1[j] + (float)b1[j];
            float m2 = (float)a2[j] + (float)b2[j];
            if (m0 > 0.f) acc[j]     += m0;
            if (m1 > 0.f) acc[4 + j] += m1;
            if (m2 > 0.f) acc[8 + j] += m2;
        }
        ecur = enext;
    }

    f16* zr = z + (long)node * DM + base;
    f16x4 o0, o1, o2;
    #pragma unroll
    for (int j = 0; j < 4; ++j) {
        o0[j] = (f16)acc[j];
        o1[j] = (f16)acc[4 + j];
        o2[j] = (f16)acc[8 + j];
    }
    *(f16x4*)&zr[0] = o0;
    *(f16x4*)&zr[4] = o1;
    *(f16x4*)&zr[8] = o2;
}

// -------- GEMM 256x256: C[M,768] = act(A[M,768] @ W + bias) ----------
// 512 thr / 8 waves (wm=wid>>2, wn=wid&3), per-wave C = 128x64. BK=64, dbuf.
// Staging: 8 async16/thread per K-tile (4 A-quarters + 4 B-quarters); wave wid
// stages rows [i*64 + wid*8, +8), slot lane&7, source col XOR-swizzled
// (slot ^ row&7). Counted vmcnt: at tile top 2 next-tile loads are in flight
// -> s_waitcnt vmcnt(2); phases 1..3 issue 2 more each (8 total for next).
#define ACT_NONE 0
#define ACT_RELU 1
#define ACT_GELU 2

#define STAGE_PAIR(i, ktile, buf)                                                            \
    async16(gA + (long)(ktile) * 64 + (long)(i) * 64 * DM, &As[buf][((i) * 64 + wid * 8) * 64]); \
    async16(gB + (long)(ktile) * 64 + (long)(i) * 64 * DM, &Bs[buf][((i) * 64 + wid * 8) * 64]);

template <int ACT>
__global__ __launch_bounds__(512, 2) void gemm256(
    const f16* __restrict__ A,      // [M,768] f16; rows may overread <=255 past M (mapped)
    const f16* __restrict__ Bt,     // [768,768] f16, Bt[n][k] = W[k][n]
    const float* __restrict__ bias, // [768] fp32
    f16* __restrict__ C,            // [M,768] f16
    int M) {
    __shared__ f16 As[2][256 * 64];
    __shared__ f16 Bs[2][256 * 64];
    int tid = threadIdx.x;
    int lane = tid & 63;
    int wid = tid >> 6;             // 0..7
    int wm = wid >> 2, wn = wid & 3;

    int wg = xcd_swizzle(blockIdx.x, gridDim.x);
    int rt = wg / 3, cb = wg - rt * 3;   // col-fastest, 3 col tiles of 256
    long rowBase = (long)rt * 256;
    const f16* Ab = A + rowBase * DM;
    const f16* Bb = Bt + (long)cb * 256 * DM;

    // staging addresses (XOR-swizzled source)
    int srow8 = lane >> 3;          // row within 8-row group == row&7
    int sslot = lane & 7;
    int scol = ((sslot ^ srow8) * 8);
    const f16* gA = Ab + (long)(wid * 8 + srow8) * DM + scol;
    const f16* gB = Bb + (long)(wid * 8 + srow8) * DM + scol;

    // read geometry
    int fm = lane & 15;
    int fq = lane >> 4;             // 0..3

    // bias preloaded BEFORE the K-loop (keeps vmcnt counting exact)
    int col0 = cb * 256 + wn * 64;
    float4 bv[4];
    #pragma unroll
    for (int ci = 0; ci < 4; ++ci)
        bv[ci] = *(const float4*)&bias[col0 + ci * 16 + fq * 4];

    f32x4 acc[8][4];
    #pragma unroll
    for (int i = 0; i < 8; ++i)
        #pragma unroll
        for (int j = 0; j < 4; ++j) acc[i][j] = (f32x4){0.f, 0.f, 0.f, 0.f};

    // prologue: stage K-tile 0 into buffer 0 (8 loads/thread)
    #pragma unroll
    for (int i = 0; i < 4; ++i) { STAGE_PAIR(i, 0, 0) }

    int cur = 0;
    for (int kt = 0; kt < DM / 64; ++kt) {
        int nxtb = cur ^ 1;
        bool pre = (kt + 1 < DM / 64);
        __builtin_amdgcn_sched_barrier(0);
        if (pre) { STAGE_PAIR(0, kt + 1, nxtb) }
        if (pre) asm volatile("s_waitcnt vmcnt(2)" ::: "memory");
        else     asm volatile("s_waitcnt vmcnt(0)" ::: "memory");
        __builtin_amdgcn_s_barrier();          // buf[cur] ready for all waves
        __builtin_amdgcn_sched_barrier(0);

        #pragma unroll
        for (int p = 0; p < 4; ++p) {
            const int rih = p & 1, kh = p >> 1;
            int rs = ((kh * 4 + fq) ^ (fm & 7)) * 8;
            f16x8 af[4], bf[4];
            #pragma unroll
            for (int r = 0; r < 4; ++r)
                af[r] = *(const f16x8*)&As[cur][(wm * 128 + (rih * 4 + r) * 16 + fm) * 64 + rs];
            #pragma unroll
            for (int c = 0; c < 4; ++c)
                bf[c] = *(const f16x8*)&Bs[cur][(wn * 64 + c * 16 + fm) * 64 + rs];
            if (pre && p > 0) { STAGE_PAIR(p, kt + 1, nxtb) }
            __builtin_amdgcn_s_setprio(1);
            #pragma unroll
            for (int c = 0; c < 4; ++c)
                #pragma unroll
                for (int r = 0; r < 4; ++r)
                    acc[rih * 4 + r][c] = __builtin_amdgcn_mfma_f32_16x16x32_f16(
                        bf[c], af[r], acc[rih * 4 + r][c], 0, 0, 0);
            __builtin_amdgcn_s_setprio(0);
            __builtin_amdgcn_s_barrier();      // phase lockstep; phase-3 barrier
        }                                      // guards next tile's overwrite
        cur = nxtb;
    }

    // epilogue: operand-swapped D: row = fm (fixed/lane), col = fq*4+r (consec)
    int row0 = (int)rowBase + wm * 128;
    #pragma unroll
    for (int ri = 0; ri < 8; ++ri) {
        int row = row0 + ri * 16 + fm;
        if (row < M) {
            #pragma unroll
            for (int ci = 0; ci < 4; ++ci) {
                int c0 = col0 + ci * 16 + fq * 4;
                f16x4 o;
                #pragma unroll
                for (int r = 0; r < 4; ++r) {
                    float v = acc[ri][ci][r] + (&bv[ci].x)[r];
                    if (ACT == ACT_RELU) v = v > 0.f ? v : 0.f;
                    if (ACT == ACT_GELU) v = gelu_f(v);
                    o[r] = (f16)v;
                }
                *(f16x4*)&C[(long)row * DM + c0] = o;
            }
        }
    }
}

extern "C" void kernel_launch(void* const* d_in, const int* in_sizes, int n_in,
                              void* d_out, int out_size, void* d_ws, size_t ws_size,
                              hipStream_t stream) {
    const int* x  = (const int*)d_in[0];
    const int* ea = (const int*)d_in[1];
    const int* ei = (const int*)d_in[2];
    const float* atom_emb  = (const float*)d_in[3];
    const float* atom_ln_g = (const float*)d_in[4];
    const float* atom_ln_b = (const float*)d_in[5];
    const float* atom_w1   = (const float*)d_in[6];
    const float* atom_b1   = (const float*)d_in[7];
    const float* atom_w2   = (const float*)d_in[8];
    const float* atom_b2   = (const float*)d_in[9];
    const float* bond_emb  = (const float*)d_in[10];
    const float* bond_ln_g = (const float*)d_in[11];
    const float* bond_ln_b = (const float*)d_in[12];
    const float* bond_w1   = (const float*)d_in[13];
    const float* bond_b1   = (const float*)d_in[14];
    const float* bond_w2   = (const float*)d_in[15];
    const float* bond_b2   = (const float*)d_in[16];
    const float* conv_w1   = (const float*)d_in[17];
    const float* conv_b1   = (const float*)d_in[18];
    const float* conv_w2   = (const float*)d_in[19];
    const float* conv_b2   = (const float*)d_in[20];
    const float* ln_g      = (const float*)d_in[21];
    const float* ln_b      = (const float*)d_in[22];

    const int N = in_sizes[0] / 9;
    const int E = in_sizes[1] / 3;
    const int V = in_sizes[10] / (3 * DM);  // bond vocab (8) -> V^3 combos (512)
    const int nC = V * V * V;
    const long SZ = (long)DM * DM;

    // ---- workspace: WT | Q | h | T | key | ids3 (~170 MiB) ----
    char* ws = (char*)d_ws;
    size_t off = 0;
    f16* WT  = (f16*)(ws + off); off += ((size_t)12 * SZ * 2 + 4095) & ~(size_t)4095;
    f16* Q   = (f16*)(ws + off); off += ((size_t)CHUNK * DM * 2 + 4095) & ~(size_t)4095;
    f16* h   = (f16*)(ws + off); off += ((size_t)N * DM * 2 + 4095) & ~(size_t)4095;
    f16* T   = (f16*)(ws + off); off += ((size_t)((nC + 255) & ~255) * DM * 2 + 4095) & ~(size_t)4095;
    int* key = (int*)(ws + off); off += ((size_t)E * 4 + 4095) & ~(size_t)4095;
    int* ids3 = (int*)(ws + off); off += ((size_t)nC * 12 + 4095) & ~(size_t)4095;
    // d_out region (N*DM fp32 = 153.6MB): low half = f16 U scratch (<=77.1MB);
    // head/next parked at +120MB, only clobbered by the final fp32 LN write.
    f16*   U    = (f16*)d_out;
    int*   head = (int*)((char*)d_out + 120000000);
    int*   nxt  = head + N;

    dim3 tb(32, 8), tg(24, 24);
    transpose768<<<tg, tb, 0, stream>>>(atom_w1, WT + 0 * SZ);
    transpose768<<<tg, tb, 0, stream>>>(atom_w2, WT + 1 * SZ);
    transpose768<<<tg, tb, 0, stream>>>(bond_w1, WT + 2 * SZ);
    transpose768<<<tg, tb, 0, stream>>>(bond_w2, WT + 3 * SZ);
    for (int l = 0; l < NLAYERS; ++l) {
        transpose768<<<tg, tb, 0, stream>>>(conv_w1 + l * SZ, WT + (4 + l) * SZ);
        transpose768<<<tg, tb, 0, stream>>>(conv_w2 + l * SZ, WT + (8 + l) * SZ);
    }

    // build dst->edges linked list + per-edge combo key (edge data is constant)
    hipMemsetAsync(head, 0xFF, (size_t)N * 4, stream);  // head = -1
    build_list_kernel<<<(E + 255) / 256, 256, 0, stream>>>(ei, E, head, nxt);
    make_key_kernel<<<(E + 255) / 256, 256, 0, stream>>>(ea, E, V, key);

    dim3 gn(3 * ((N + 255) / 256));   // 1-D, XCD swizzle inside the kernel

    // AtomEncoder: h = gelu(LN(sum emb) @ w1 + b1) @ w2 + b2   (Q -> U(d_out) -> h)
    embed_ln_wave<<<(N + 3) / 4, 256, 0, stream>>>(x, 9, 128, atom_emb, atom_ln_g, atom_ln_b, Q, N);
    gemm256<ACT_GELU><<<gn, 512, 0, stream>>>(Q, WT + 0 * SZ, atom_b1, U, N);
    gemm256<ACT_NONE><<<gn, 512, 0, stream>>>(U, WT + 1 * SZ, atom_b2, h, N);

    // BondEncoder on the V^3 combo table only: Q -> U(d_out) -> T
    make_combo_ids<<<(nC + 255) / 256, 256, 0, stream>>>(V, nC, ids3);
    embed_ln_wave<<<(nC + 3) / 4, 256, 0, stream>>>(ids3, 3, V, bond_emb, bond_ln_g, bond_ln_b, Q, nC);
    dim3 gt(3 * ((nC + 255) / 256));
    gemm256<ACT_GELU><<<gt, 512, 0, stream>>>(Q, WT + 2 * SZ, bond_b1, U, nC);
    gemm256<ACT_NONE><<<gt, 512, 0, stream>>>(U, WT + 3 * SZ, bond_b2, T, nC);

    for (int l = 0; l < NLAYERS; ++l) {
        // z = h + sum_{j->i} relu(h[src] + T[key])  -> Q (f16), pure gather
        gather_agg_kernel<<<(N + 3) / 4, 256, 0, stream>>>(ei, head, nxt, key, h, T, Q, N);
        gemm256<ACT_RELU><<<gn, 512, 0, stream>>>(Q, WT + (4 + l) * SZ, conv_b1 + l * DM, U, N);  // U -> d_out
        gemm256<ACT_NONE><<<gn, 512, 0, stream>>>(U, WT + (8 + l) * SZ, conv_b2 + l * DM, Q, N);  // V -> Q
        if (l == NLAYERS - 1) {
            gelu_res_ln_wave<float><<<(N + 3) / 4, 256, 0, stream>>>(Q, h, ln_g + l * DM, ln_b + l * DM, (float*)d_out, N);
        } else {
            gelu_res_ln_wave<f16><<<(N + 3) / 4, 256, 0, stream>>>(Q, h, ln_g + l * DM, ln_b + l * DM, h, N);
        }
    }
}

// Round 11
// 1375.437 us; speedup vs baseline: 1.2132x; 1.2132x over previous
//
#include <hip/hip_runtime.h>

// GraphEncoder: GINE-style GNN, D=768, 4 layers. fp32 I/O, f16 intermediates +
// f16 MFMA GEMMs, fp32 accumulate/LN/scatter math.
//
// Round 13 (resubmit of round 12 -- container infra failure, no counters):
// 128^2 BK=64 single-buffer GEMM, pipelined via barrier semantics (no counted
// vmcnt, so the compiler cannot defeat it):
//   syncthreads(a)            // stage(kt) visible (own vmcnt drain + barrier)
//   ds_read all 16 frags      // -> VGPRs
//   syncthreads(b)            // lgkmcnt(0): all reads retired block-wide
//   stage(kt+1)               // overwrite LDS; latency hides under MFMAs
//   sched_barrier(0)          // pin stage issue before MFMA cluster
//   32 MFMAs                  // register-only
// The stage latency (~250-300cy L2) overlaps the MFMA cluster + next iter's
// ds_reads instead of being exposed at a drain every iteration. The drain at
// barrier (a) of iteration kt+1 sits AFTER iteration kt's MFMAs (in-order).
//
// Kept: operand-swapped MFMA epilogue (8B f16x4 C stores, WRITE=ideal),
// XCD-chunked grid swizzle (FETCH 54MB), LDS XOR swizzle slot^=row&7
// both-sides, __expf gelu, wave-per-row LN kernels, deduped bond encoder,
// linked-list gather aggregation.
//
// Workspace: [WT 12x768x768 f16 | Q 50048x768 f16 | h Nx768 f16 | T | key | ids3]
// d_out (Nx768 fp32, 153.6MB): low half = f16 U scratch; head/next parked at
// +120MB (clobbered only by the final fp32 LN write, which covers all of d_out).

#define DM 768
#define NLAYERS 4
#define CHUNK 50048  // row capacity for Q (multiple of 128, >= N)

typedef _Float16 f16;
typedef __attribute__((ext_vector_type(8))) _Float16 f16x8;
typedef __attribute__((ext_vector_type(4))) _Float16 f16x4;
typedef __attribute__((ext_vector_type(4))) float f32x4;

// gelu(x) = 0.5x(1+tanh(0.79788456(x+0.044715x^3))), tanh via exp:
// tanh(u) = sign(u) * (1 - a)/(1 + a), a = exp(-2|u|)  (a->0 saturates cleanly)
__device__ __forceinline__ float gelu_f(float x) {
    float u = 0.7978845608028654f * (x + 0.044715f * x * x * x);
    float a = __expf(-2.0f * fabsf(u));
    float t = (1.0f - a) / (1.0f + a);
    t = copysignf(t, u);
    return 0.5f * x * (1.0f + t);
}
__device__ __forceinline__ void async16(const void* g, void* l) {
    __builtin_amdgcn_global_load_lds((const __attribute__((address_space(1))) void*)g,
                                     (__attribute__((address_space(3))) void*)l,
                                     16, 0, 0);
}

// bijective XCD-chunked swizzle (m204): XCD k = b%8 gets a contiguous range of
// work ids; within the range, original b/8 order is preserved.
__device__ __forceinline__ int xcd_swizzle(int b, int nb) {
    int xcd = b & 7;
    int pos = b >> 3;
    int q = nb >> 3, r = nb & 7;
    int base = (xcd < r) ? xcd * (q + 1) : r * (q + 1) + (xcd - r) * q;
    return base + pos;
}

// -------- weight transpose + fp32->fp16: Wt[n][k] = W[k][n], 768x768 ----------
__global__ __launch_bounds__(256) void transpose768(
    const float* __restrict__ W, f16* __restrict__ Wt) {
    __shared__ float t[32][33];
    int tx = threadIdx.x, ty = threadIdx.y;
    int c0 = blockIdx.x * 32, r0 = blockIdx.y * 32;
    #pragma unroll
    for (int j = 0; j < 32; j += 8) t[ty + j][tx] = W[(r0 + ty + j) * DM + c0 + tx];
    __syncthreads();
    #pragma unroll
    for (int j = 0; j < 32; j += 8) Wt[(long)(c0 + ty + j) * DM + r0 + tx] = (f16)t[tx][ty + j];
}

// -------- embedding-sum + LayerNorm, wave-per-row (no LDS, no barriers) ------
__global__ __launch_bounds__(256) void embed_ln_wave(
    const int* __restrict__ ids, int F, int V,
    const float* __restrict__ emb,
    const float* __restrict__ g, const float* __restrict__ b,
    f16* __restrict__ out, int M) {
    int row = blockIdx.x * 4 + (threadIdx.x >> 6);
    if (row >= M) return;
    int lane = threadIdx.x & 63;
    int base = lane * 12;

    float v[12];
    #pragma unroll
    for (int j = 0; j < 12; ++j) v[j] = 0.f;
    for (int f = 0; f < F; ++f) {
        int id = ids[(long)row * F + f];
        const float* r = emb + ((long)f * V + id) * DM + base;
        float4 r0 = *(const float4*)&r[0];
        float4 r1 = *(const float4*)&r[4];
        float4 r2 = *(const float4*)&r[8];
        v[0] += r0.x; v[1] += r0.y; v[2]  += r0.z; v[3]  += r0.w;
        v[4] += r1.x; v[5] += r1.y; v[6]  += r1.z; v[7]  += r1.w;
        v[8] += r2.x; v[9] += r2.y; v[10] += r2.z; v[11] += r2.w;
    }
    float s1 = 0.f, s2 = 0.f;
    #pragma unroll
    for (int j = 0; j < 12; ++j) { s1 += v[j]; s2 += v[j] * v[j]; }
    #pragma unroll
    for (int off = 32; off > 0; off >>= 1) {
        s1 += __shfl_xor(s1, off);
        s2 += __shfl_xor(s2, off);
    }
    float mean = s1 * (1.f / DM);
    float var = s2 * (1.f / DM) - mean * mean;
    float rstd = rsqrtf(var + 1e-5f);

    float4 gv0 = *(const float4*)&g[base], gv1 = *(const float4*)&g[base + 4], gv2 = *(const float4*)&g[base + 8];
    float4 bv0 = *(const float4*)&b[base], bv1 = *(const float4*)&b[base + 4], bv2 = *(const float4*)&b[base + 8];
    float gg[12] = {gv0.x, gv0.y, gv0.z, gv0.w, gv1.x, gv1.y, gv1.z, gv1.w, gv2.x, gv2.y, gv2.z, gv2.w};
    float bb[12] = {bv0.x, bv0.y, bv0.z, bv0.w, bv1.x, bv1.y, bv1.z, bv1.w, bv2.x, bv2.y, bv2.z, bv2.w};
    f16* o = out + (long)row * DM + base;
    #pragma unroll
    for (int q = 0; q < 3; ++q) {
        f16x4 ov;
        #pragma unroll
        for (int r = 0; r < 4; ++r)
            ov[r] = (f16)((v[q * 4 + r] - mean) * rstd * gg[q * 4 + r] + bb[q * 4 + r]);
        *(f16x4*)&o[q * 4] = ov;
    }
}

// -------- gelu(U) + h_in -> LayerNorm -> out, wave-per-row ----------
template <typename OUT>
__global__ __launch_bounds__(256) void gelu_res_ln_wave(
    const f16* __restrict__ U, const f16* __restrict__ hin,
    const float* __restrict__ g, const float* __restrict__ b,
    OUT* __restrict__ out, int M) {
    int row = blockIdx.x * 4 + (threadIdx.x >> 6);
    if (row >= M) return;
    int lane = threadIdx.x & 63;
    int base = lane * 12;

    const f16* up = U + (long)row * DM + base;
    const f16* hp = hin + (long)row * DM + base;
    float v[12];
    #pragma unroll
    for (int q = 0; q < 3; ++q) {
        f16x4 uv = *(const f16x4*)&up[q * 4];
        f16x4 hv = *(const f16x4*)&hp[q * 4];
        #pragma unroll
        for (int r = 0; r < 4; ++r)
            v[q * 4 + r] = gelu_f((float)uv[r]) + (float)hv[r];
    }
    float s1 = 0.f, s2 = 0.f;
    #pragma unroll
    for (int j = 0; j < 12; ++j) { s1 += v[j]; s2 += v[j] * v[j]; }
    #pragma unroll
    for (int off = 32; off > 0; off >>= 1) {
        s1 += __shfl_xor(s1, off);
        s2 += __shfl_xor(s2, off);
    }
    float mean = s1 * (1.f / DM);
    float var = s2 * (1.f / DM) - mean * mean;
    float rstd = rsqrtf(var + 1e-5f);

    float4 gv0 = *(const float4*)&g[base], gv1 = *(const float4*)&g[base + 4], gv2 = *(const float4*)&g[base + 8];
    float4 bv0 = *(const float4*)&b[base], bv1 = *(const float4*)&b[base + 4], bv2 = *(const float4*)&b[base + 8];
    float gg[12] = {gv0.x, gv0.y, gv0.z, gv0.w, gv1.x, gv1.y, gv1.z, gv1.w, gv2.x, gv2.y, gv2.z, gv2.w};
    float bb[12] = {bv0.x, bv0.y, bv0.z, bv0.w, bv1.x, bv1.y, bv1.z, bv1.w, bv2.x, bv2.y, bv2.z, bv2.w};
    #pragma unroll
    for (int q = 0; q < 3; ++q) {
        float w0 = (v[q * 4 + 0] - mean) * rstd * gg[q * 4 + 0] + bb[q * 4 + 0];
        float w1 = (v[q * 4 + 1] - mean) * rstd * gg[q * 4 + 1] + bb[q * 4 + 1];
        float w2 = (v[q * 4 + 2] - mean) * rstd * gg[q * 4 + 2] + bb[q * 4 + 2];
        float w3 = (v[q * 4 + 3] - mean) * rstd * gg[q * 4 + 3] + bb[q * 4 + 3];
        if constexpr (sizeof(OUT) == 2) {
            f16x4 ov; ov[0] = (f16)w0; ov[1] = (f16)w1; ov[2] = (f16)w2; ov[3] = (f16)w3;
            *(f16x4*)&out[(long)row * DM + base + q * 4] = ov;
        } else {
            float4 ov; ov.x = w0; ov.y = w1; ov.z = w2; ov.w = w3;
            *(float4*)&out[(long)row * DM + base + q * 4] = ov;
        }
    }
}

// -------- bond-combo helpers: ids for all V^3 combos; per-edge key ----------
__global__ __launch_bounds__(256) void make_combo_ids(
    int V, int nC, int* __restrict__ ids) {
    int c = blockIdx.x * 256 + threadIdx.x;
    if (c >= nC) return;
    ids[c * 3 + 0] = c / (V * V);
    ids[c * 3 + 1] = (c / V) % V;
    ids[c * 3 + 2] = c % V;
}
__global__ __launch_bounds__(256) void make_key_kernel(
    const int* __restrict__ ea, int E, int V, int* __restrict__ key) {
    int e = blockIdx.x * 256 + threadIdx.x;
    if (e >= E) return;
    key[e] = (ea[e * 3 + 0] * V + ea[e * 3 + 1]) * V + ea[e * 3 + 2];
}

// -------- build per-dst edge linked list (once; edge_index is layer-invariant) --
__global__ __launch_bounds__(256) void build_list_kernel(
    const int* __restrict__ ei, int E,
    int* __restrict__ head, int* __restrict__ nxt) {
    int e = blockIdx.x * 256 + threadIdx.x;
    if (e >= E) return;
    int dst = ei[E + e];
    nxt[e] = atomicExch(&head[dst], e);  // device-scope; order irrelevant (sum)
}

// -------- per-node gather aggregation: z[n] = h[n] + sum relu(h[src]+T[key]) --
__global__ __launch_bounds__(256) void gather_agg_kernel(
    const int* __restrict__ ei,
    const int* __restrict__ head, const int* __restrict__ nxt,
    const int* __restrict__ key,
    const f16* __restrict__ h, const f16* __restrict__ T,
    f16* __restrict__ z, int N) {
    int node = blockIdx.x * 4 + (threadIdx.x >> 6);
    if (node >= N) return;
    int lane = threadIdx.x & 63;
    int base = lane * 12;

    const f16* hr = h + (long)node * DM + base;
    f16x4 v0 = *(const f16x4*)&hr[0];
    f16x4 v1 = *(const f16x4*)&hr[4];
    f16x4 v2 = *(const f16x4*)&hr[8];
    float acc[12];
    #pragma unroll
    for (int j = 0; j < 4; ++j) {
        acc[j]     = (float)v0[j];
        acc[4 + j] = (float)v1[j];
        acc[8 + j] = (float)v2[j];
    }

    int ecur = head[node];
    while (ecur >= 0) {
        int enext = nxt[ecur];          // issue chase early; rows overlap it
        int src = ei[ecur];
        int kq = key[ecur];
        const f16* sr = h + (long)src * DM + base;
        const f16* er = T + (long)kq * DM + base;
        f16x4 a0 = *(const f16x4*)&sr[0];
        f16x4 a1 = *(const f16x4*)&sr[4];
        f16x4 a2 = *(const f16x4*)&sr[8];
        f16x4 b0 = *(const f16x4*)&er[0];
        f16x4 b1 = *(const f16x4*)&er[4];
        f16x4 b2 = *(const f16x4*)&er[8];
        #pragma unroll
        for (int j = 0; j < 4; ++j) {
            float m0 = (float)a0[j] + (float)b0[j];
            float m1 = (float)a1[j] + (float)b1[j];
            float m2 = (float)a2[j] + (float)b2[j];
            if (m0 > 0.f) acc[j]     += m0;
            if (m1 > 0.f) acc[4 + j] += m1;
            if (m2 > 0.f) acc[8 + j] += m2;
        }
        ecur = enext;
    }

    f16* zr = z + (long)node * DM + base;
    f16x4 o0, o1, o2;
    #pragma unroll
    for (int j = 0; j < 4; ++j) {
        o0[j] = (f16)acc[j];
        o1[j] = (f16)acc[4 + j];
        o2[j] = (f16)acc[8 + j];
    }
    *(f16x4*)&zr[0] = o0;
    *(f16x4*)&zr[4] = o1;
    *(f16x4*)&zr[8] = o2;
}

// -------- GEMM: C[M,768] = act(A[M,768] @ W + bias), Bt[n][k] = W[k][n] ----------
// 1-D grid, XCD-chunked swizzle. MFMA operands swapped (transposed D) for 8B
// f16x4 C stores. BK=64 single-buffered (32KB LDS), pipelined via barrier
// semantics: reads -> syncthreads -> stage(kt+1) -> sched_barrier -> MFMAs.
// LDS tile [128][64] f16 (128B rows): 16B-slot swizzle s ^= row&7 on BOTH the
// staging source column and the ds_read column (rule #21).
#define ACT_NONE 0
#define ACT_RELU 1
#define ACT_GELU 2

template <int ACT>
__global__ __launch_bounds__(256, 2) void gemm768(
    const f16* __restrict__ A,      // [M,768] f16; rows may overread <=127 past M (mapped)
    const f16* __restrict__ Bt,     // [768,768] f16, Bt[n][k] = W[k][n]
    const float* __restrict__ bias, // [768] fp32
    f16* __restrict__ C,            // [M,768] f16
    int M) {
    __shared__ f16 As[128 * 64];
    __shared__ f16 Bs[128 * 64];
    int tid = threadIdx.x;
    int lane = tid & 63;
    int wid = tid >> 6;
    int wm = wid >> 1, wn = wid & 1;

    int wg = xcd_swizzle(blockIdx.x, gridDim.x);
    int rt = wg / 6, cb = wg - rt * 6;
    long rowBase = (long)rt * 128;
    const f16* Ab = A + rowBase * DM;
    const f16* Bb = Bt + (long)cb * 128 * DM;

    f32x4 acc[4][4];  // acc[ci][ri]: ci = col subtile (from Bt), ri = row subtile
    #pragma unroll
    for (int i = 0; i < 4; ++i)
        #pragma unroll
        for (int j = 0; j < 4; ++j) acc[i][j] = (f32x4){0.f, 0.f, 0.f, 0.f};

    // ---- staging geometry (BK=64): wave stages rows [wid*32, wid*32+32) of
    // A and B; each async16 covers 8 rows x 8 slots. lane -> row srow, slot.
    int sr = wid * 32;
    int srow = lane >> 3;              // 0..7 within the 8-row group
    int sslot = lane & 7;              // 16B slot 0..7
    int scol = ((sslot ^ srow) * 8);   // swizzled source column (elems)
    const f16* gA = Ab + (long)(sr + srow) * DM + scol;
    const f16* gB = Bb + (long)(sr + srow) * DM + scol;

    // ---- read geometry: frag row r = base + fm, slot = kslot ^ (fm&7)
    int fm = lane & 15;
    int fq = lane >> 4;                // 0..3
    int rs0 = ((fq ^ (fm & 7)) * 8);         // kk=0 half: kslot = fq
    int rs1 = (((4 + fq) ^ (fm & 7)) * 8);   // kk=32 half: kslot = 4+fq

    // prologue: stage K-tile 0
    #pragma unroll
    for (int j = 0; j < 4; ++j) {
        async16(gA + j * 8 * DM, &As[(sr + j * 8) * 64]);
        async16(gB + j * 8 * DM, &Bs[(sr + j * 8) * 64]);
    }

    for (int kt = 0; kt < DM / 64; ++kt) {
        __syncthreads();   // (a) own vmcnt(0) + barrier: stage(kt) visible

        f16x8 af0[4], bf0[4], af1[4], bf1[4];
        #pragma unroll
        for (int i = 0; i < 4; ++i) {
            int ra = (wm * 64 + i * 16 + fm) * 64;
            af0[i] = *(const f16x8*)&As[ra + rs0];
            af1[i] = *(const f16x8*)&As[ra + rs1];
        }
        #pragma unroll
        for (int j = 0; j < 4; ++j) {
            int rb = (wn * 64 + j * 16 + fm) * 64;
            bf0[j] = *(const f16x8*)&Bs[rb + rs0];
            bf1[j] = *(const f16x8*)&Bs[rb + rs1];
        }
        __syncthreads();   // (b) lgkmcnt(0): all reads retired block-wide

        if (kt + 1 < DM / 64) {
            int k0 = (kt + 1) * 64;
            #pragma unroll
            for (int j = 0; j < 4; ++j) {
                async16(gA + k0 + j * 8 * DM, &As[(sr + j * 8) * 64]);
                async16(gB + k0 + j * 8 * DM, &Bs[(sr + j * 8) * 64]);
            }
        }
        __builtin_amdgcn_sched_barrier(0);  // stage issued BEFORE MFMA cluster

        #pragma unroll
        for (int ci = 0; ci < 4; ++ci)
            #pragma unroll
            for (int ri = 0; ri < 4; ++ri)
                acc[ci][ri] = __builtin_amdgcn_mfma_f32_16x16x32_f16(bf0[ci], af0[ri], acc[ci][ri], 0, 0, 0);
        #pragma unroll
        for (int ci = 0; ci < 4; ++ci)
            #pragma unroll
            for (int ri = 0; ri < 4; ++ri)
                acc[ci][ri] = __builtin_amdgcn_mfma_f32_16x16x32_f16(bf1[ci], af1[ri], acc[ci][ri], 0, 0, 0);
    }

    int row0 = (int)rowBase + wm * 64;
    int col0 = cb * 128 + wn * 64;
    // bias: 4 consecutive cols per (ci), 16B-aligned
    float4 bv[4];
    #pragma unroll
    for (int ci = 0; ci < 4; ++ci)
        bv[ci] = *(const float4*)&bias[col0 + ci * 16 + (lane >> 4) * 4];
    #pragma unroll
    for (int ri = 0; ri < 4; ++ri) {
        int row = row0 + ri * 16 + (lane & 15);
        if (row < M) {
            #pragma unroll
            for (int ci = 0; ci < 4; ++ci) {
                int c0 = col0 + ci * 16 + (lane >> 4) * 4;
                f16x4 o;
                #pragma unroll
                for (int r = 0; r < 4; ++r) {
                    float v = acc[ci][ri][r] + (&bv[ci].x)[r];
                    if (ACT == ACT_RELU) v = v > 0.f ? v : 0.f;
                    if (ACT == ACT_GELU) v = gelu_f(v);
                    o[r] = (f16)v;
                }
                *(f16x4*)&C[(long)row * DM + c0] = o;
            }
        }
    }
}

extern "C" void kernel_launch(void* const* d_in, const int* in_sizes, int n_in,
                              void* d_out, int out_size, void* d_ws, size_t ws_size,
                              hipStream_t stream) {
    const int* x  = (const int*)d_in[0];
    const int* ea = (const int*)d_in[1];
    const int* ei = (const int*)d_in[2];
    const float* atom_emb  = (const float*)d_in[3];
    const float* atom_ln_g = (const float*)d_in[4];
    const float* atom_ln_b = (const float*)d_in[5];
    const float* atom_w1   = (const float*)d_in[6];
    const float* atom_b1   = (const float*)d_in[7];
    const float* atom_w2   = (const float*)d_in[8];
    const float* atom_b2   = (const float*)d_in[9];
    const float* bond_emb  = (const float*)d_in[10];
    const float* bond_ln_g = (const float*)d_in[11];
    const float* bond_ln_b = (const float*)d_in[12];
    const float* bond_w1   = (const float*)d_in[13];
    const float* bond_b1   = (const float*)d_in[14];
    const float* bond_w2   = (const float*)d_in[15];
    const float* bond_b2   = (const float*)d_in[16];
    const float* conv_w1   = (const float*)d_in[17];
    const float* conv_b1   = (const float*)d_in[18];
    const float* conv_w2   = (const float*)d_in[19];
    const float* conv_b2   = (const float*)d_in[20];
    const float* ln_g      = (const float*)d_in[21];
    const float* ln_b      = (const float*)d_in[22];

    const int N = in_sizes[0] / 9;
    const int E = in_sizes[1] / 3;
    const int V = in_sizes[10] / (3 * DM);  // bond vocab (8) -> V^3 combos (512)
    const int nC = V * V * V;
    const long SZ = (long)DM * DM;

    // ---- workspace: WT | Q | h | T | key | ids3 (~170 MiB) ----
    char* ws = (char*)d_ws;
    size_t off = 0;
    f16* WT  = (f16*)(ws + off); off += ((size_t)12 * SZ * 2 + 4095) & ~(size_t)4095;
    f16* Q   = (f16*)(ws + off); off += ((size_t)CHUNK * DM * 2 + 4095) & ~(size_t)4095;
    f16* h   = (f16*)(ws + off); off += ((size_t)N * DM * 2 + 4095) & ~(size_t)4095;
    f16* T   = (f16*)(ws + off); off += ((size_t)((nC + 127) & ~127) * DM * 2 + 4095) & ~(size_t)4095;
    int* key = (int*)(ws + off); off += ((size_t)E * 4 + 4095) & ~(size_t)4095;
    int* ids3 = (int*)(ws + off); off += ((size_t)nC * 12 + 4095) & ~(size_t)4095;
    // d_out region (N*DM fp32 = 153.6MB): low half = f16 U scratch (<=76.9MB);
    // head/next parked at +120MB, only clobbered by the final fp32 LN write.
    f16*   U    = (f16*)d_out;
    int*   head = (int*)((char*)d_out + 120000000);
    int*   nxt  = head + N;

    dim3 tb(32, 8), tg(24, 24);
    transpose768<<<tg, tb, 0, stream>>>(atom_w1, WT + 0 * SZ);
    transpose768<<<tg, tb, 0, stream>>>(atom_w2, WT + 1 * SZ);
    transpose768<<<tg, tb, 0, stream>>>(bond_w1, WT + 2 * SZ);
    transpose768<<<tg, tb, 0, stream>>>(bond_w2, WT + 3 * SZ);
    for (int l = 0; l < NLAYERS; ++l) {
        transpose768<<<tg, tb, 0, stream>>>(conv_w1 + l * SZ, WT + (4 + l) * SZ);
        transpose768<<<tg, tb, 0, stream>>>(conv_w2 + l * SZ, WT + (8 + l) * SZ);
    }

    // build dst->edges linked list + per-edge combo key (edge data is constant)
    hipMemsetAsync(head, 0xFF, (size_t)N * 4, stream);  // head = -1
    build_list_kernel<<<(E + 255) / 256, 256, 0, stream>>>(ei, E, head, nxt);
    make_key_kernel<<<(E + 255) / 256, 256, 0, stream>>>(ea, E, V, key);

    int rtN = (N + 127) / 128;
    dim3 gn(6 * rtN);   // 1-D, XCD-chunked swizzle inside the kernel

    // AtomEncoder: h = gelu(LN(sum emb) @ w1 + b1) @ w2 + b2   (Q -> U(d_out) -> h)
    embed_ln_wave<<<(N + 3) / 4, 256, 0, stream>>>(x, 9, 128, atom_emb, atom_ln_g, atom_ln_b, Q, N);
    gemm768<ACT_GELU><<<gn, 256, 0, stream>>>(Q, WT + 0 * SZ, atom_b1, U, N);
    gemm768<ACT_NONE><<<gn, 256, 0, stream>>>(U, WT + 1 * SZ, atom_b2, h, N);

    // BondEncoder on the V^3 combo table only: Q -> U(d_out) -> T
    make_combo_ids<<<(nC + 255) / 256, 256, 0, stream>>>(V, nC, ids3);
    embed_ln_wave<<<(nC + 3) / 4, 256, 0, stream>>>(ids3, 3, V, bond_emb, bond_ln_g, bond_ln_b, Q, nC);
    dim3 gt(6 * ((nC + 127) / 128));
    gemm768<ACT_GELU><<<gt, 256, 0, stream>>>(Q, WT + 2 * SZ, bond_b1, U, nC);
    gemm768<ACT_NONE><<<gt, 256, 0, stream>>>(U, WT + 3 * SZ, bond_b2, T, nC);

    for (int l = 0; l < NLAYERS; ++l) {
        // z = h + sum_{j->i} relu(h[src] + T[key])  -> Q (f16), pure gather
        gather_agg_kernel<<<(N + 3) / 4, 256, 0, stream>>>(ei, head, nxt, key, h, T, Q, N);
        gemm768<ACT_RELU><<<gn, 256, 0, stream>>>(Q, WT + (4 + l) * SZ, conv_b1 + l * DM, U, N);  // U -> d_out
        gemm768<ACT_NONE><<<gn, 256, 0, stream>>>(U, WT + (8 + l) * SZ, conv_b2 + l * DM, Q, N);  // V -> Q
        if (l == NLAYERS - 1) {
            gelu_res_ln_wave<float><<<(N + 3) / 4, 256, 0, stream>>>(Q, h, ln_g + l * DM, ln_b + l * DM, (float*)d_out, N);
        } else {
            gelu_res_ln_wave<f16><<<(N + 3) / 4, 256, 0, stream>>>(Q, h, ln_g + l * DM, ln_b + l * DM, h, N);
        }
    }
}